// Round 6
// baseline (205.251 us; speedup 1.0000x reference)
//
#include <hip/hip_runtime.h>

// B=16, D=256, L=256, T=1000, K=3, DW=4, DC=2, CH=8

typedef short v8s __attribute__((ext_vector_type(8)));
typedef _Float16 v8h __attribute__((ext_vector_type(8)));
typedef float f4 __attribute__((ext_vector_type(4)));

__device__ __forceinline__ float bf2f(unsigned short h) {
  return __uint_as_float(((unsigned int)h) << 16);
}
__device__ __forceinline__ unsigned short f2bf(float f) {
  unsigned int u = __float_as_uint(f);
  u = (u + 0x7FFFu + ((u >> 16) & 1u)) >> 16;
  return (unsigned short)u;
}
__device__ __forceinline__ float swishf(float x) {
  return x * __builtin_amdgcn_rcpf(1.f + __expf(-x));
}

// =======================================================================
// K_PREP: level-0 work, branch on blockIdx.x
// =======================================================================
__global__ __launch_bounds__(256) void k_prep(
    const float* __restrict__ dur, const float* __restrict__ ph,
    const float* __restrict__ liWw,
    const float* __restrict__ cvWw, const float* __restrict__ pjWw,
    const float* __restrict__ pjbw,
    const float* __restrict__ cvWc, const float* __restrict__ pjWc,
    const float* __restrict__ pjbc,
    float* __restrict__ sk, int* __restrict__ frame_len,
    unsigned short* __restrict__ Mb, float* __restrict__ bK,
    unsigned short* __restrict__ LWT, unsigned short* __restrict__ phT) {
  __shared__ float sm[32 * 33];
  int blk = blockIdx.x, tid = threadIdx.x;
  if (blk < 16) {
    int b = blk, l = tid;
    float d = dur[b * 256 + l];
    sm[l] = d;
    __syncthreads();
    for (int off = 1; off < 256; off <<= 1) {
      float v = (l >= off) ? sm[l - off] : 0.f;
      __syncthreads();
      sm[l] += v;
      __syncthreads();
    }
    sk[b * 256 + l] = sm[l] - d;
    if (l == 255) {
      int fl = (int)rintf(sm[255]);
      frame_len[b] = min(max(fl, 0), 1000);
    }
  } else if (blk < 64) {
    int x = blk - 16;
    int br = x / 24, ck = x % 24;
    int ch = ck / 3, k = ck % 3;
    const float* convW = br ? cvWc : cvWw;
    const float* projW = br ? pjWc : pjWw;
    const float* projb = br ? pjbc : pjbw;
    int d = tid;
    float acc = 0.f;
    for (int o = 0; o < 256; o++)
      acc += convW[ch * 768 + o * 3 + k] * projW[o * 256 + d];
    Mb[(br * 24 + ck) * 256 + d] = f2bf(acc);
    if (d == 0) {
      float bb = 0.f;
      for (int o = 0; o < 256; o++)
        bb += convW[ch * 768 + o * 3 + k] * projb[o];
      bK[br * 24 + ck] = bb;
    }
  } else if (blk < 320) {
    int idx = blk - 64;
    int kt = idx & 31, ot = idx >> 5;
    int tx = tid & 31, ty = tid >> 5;
#pragma unroll
    for (int r = 0; r < 4; r++) {
      int row = ty + r * 8;
      sm[row * 33 + tx] = liWw[(size_t)(kt * 32 + row) * 256 + ot * 32 + tx];
    }
    __syncthreads();
#pragma unroll
    for (int r = 0; r < 4; r++) {
      int row = ty + r * 8;
      LWT[(size_t)(ot * 32 + row) * 1024 + kt * 32 + tx] =
          f2bf(sm[tx * 33 + row]);
    }
  } else {
    int idx = blk - 320;
    int ht = idx & 7, lt = (idx >> 3) & 7, b = idx >> 6;
    int tx = tid & 31, ty = tid >> 5;
#pragma unroll
    for (int r = 0; r < 4; r++) {
      int row = ty + r * 8;
      sm[row * 33 + tx] =
          ph[(size_t)b * 65536 + (size_t)(ht * 32 + row) * 256 + lt * 32 + tx];
    }
    __syncthreads();
#pragma unroll
    for (int r = 0; r < 4; r++) {
      int row = ty + r * 8;
      phT[(size_t)b * 65536 + (size_t)(lt * 32 + row) * 256 + ht * 32 + tx] =
          f2bf(sm[tx * 33 + row]);
    }
  }
}

// =======================================================================
// K_CONVG: blk [0,16)   = MFMA conv -> hw, hc (uses LDS)
//          blk [16,272) = gemmG, BARRIER-LESS: A/B frags direct from L2.
//   per (b,q): M=256(o) x N=256(l) x K=256(h), 4 blocks of 128x128.
// =======================================================================
__global__ __launch_bounds__(256) void k_convG(
    const unsigned short* __restrict__ phT, const unsigned short* __restrict__ Mb,
    const float* __restrict__ bK, const float* __restrict__ cvbw,
    const float* __restrict__ cvbc, const float* __restrict__ dur,
    const unsigned short* __restrict__ LWT,
    float* __restrict__ hw, float* __restrict__ hc,
    _Float16* __restrict__ G) {
  __shared__ __align__(16) float C[256 * 49];  // conv only
  int blk = blockIdx.x;
  int tid = threadIdx.x, wave = tid >> 6, lane = tid & 63;
  int quad = lane >> 4, col = lane & 15;
  if (blk < 16) {
    int b = blk;
    int l0 = wave * 64;
    const unsigned short* Ab = phT + (size_t)b * 65536;
    f4 acc[4][3] = {};
#pragma unroll
    for (int k0 = 0; k0 < 256; k0 += 32) {
      v8s af[4], bf[3];
#pragma unroll
      for (int lt = 0; lt < 4; lt++)
        af[lt] = *(const v8s*)(Ab + (size_t)(l0 + lt * 16 + col) * 256 + k0 + quad * 8);
#pragma unroll
      for (int ct = 0; ct < 3; ct++)
        bf[ct] = *(const v8s*)(Mb + (size_t)(ct * 16 + col) * 256 + k0 + quad * 8);
#pragma unroll
      for (int lt = 0; lt < 4; lt++)
#pragma unroll
        for (int ct = 0; ct < 3; ct++)
          acc[lt][ct] = __builtin_amdgcn_mfma_f32_16x16x32_bf16(af[lt], bf[ct],
                                                                acc[lt][ct], 0, 0, 0);
    }
#pragma unroll
    for (int lt = 0; lt < 4; lt++)
#pragma unroll
      for (int ct = 0; ct < 3; ct++)
#pragma unroll
        for (int r = 0; r < 4; r++)
          C[(l0 + lt * 16 + quad * 4 + r) * 49 + ct * 16 + col] = acc[lt][ct][r];
    __syncthreads();
    int l = tid;
    float dv = dur[b * 256 + l];
    bool vld = (dv != 0.f);
#pragma unroll
    for (int br = 0; br < 2; br++) {
      const float* convb = br ? cvbc : cvbw;
      float* dst = br ? hc : hw;
#pragma unroll
      for (int ch = 0; ch < 8; ch++) {
        int ck = br * 24 + ch * 3;
        float v = convb[ch] + bK[ck + 1] + C[l * 49 + ck + 1];
        if (l > 0) v += bK[ck + 0] + C[(l - 1) * 49 + ck + 0];
        if (l < 255) v += bK[ck + 2] + C[(l + 1) * 49 + ck + 2];
        v = swishf(v);
        dst[((size_t)(b * 256 + l)) * 8 + ch] = vld ? v : 0.f;
      }
    }
  } else {
    int idx = blk - 16;
    int b = idx >> 4;
    int sub = idx & 15;
    int q = sub >> 2, quadr = sub & 3;
    int mo = (quadr >> 1) * 128, nl = (quadr & 1) * 128;
    int wm = (wave & 1) * 64, wn = (wave >> 1) * 64;
    const unsigned short* Ag = LWT + (size_t)q * 256;
    const unsigned short* Bg = phT + (size_t)b * 65536;
    f4 acc[4][4] = {};
#pragma unroll
    for (int k0 = 0; k0 < 256; k0 += 32) {
      v8s af[4], bf[4];
#pragma unroll
      for (int mt = 0; mt < 4; mt++)
        af[mt] = *(const v8s*)(Ag + (size_t)(mo + wm + mt * 16 + col) * 1024 +
                               k0 + quad * 8);
#pragma unroll
      for (int nt = 0; nt < 4; nt++)
        bf[nt] = *(const v8s*)(Bg + (size_t)(nl + wn + nt * 16 + col) * 256 +
                               k0 + quad * 8);
#pragma unroll
      for (int mt = 0; mt < 4; mt++)
#pragma unroll
        for (int nt = 0; nt < 4; nt++)
          acc[mt][nt] = __builtin_amdgcn_mfma_f32_16x16x32_bf16(af[mt], bf[nt],
                                                                acc[mt][nt], 0, 0, 0);
    }
    _Float16* Gb = G + (size_t)b * 262144 + q * 256;
#pragma unroll
    for (int mt = 0; mt < 4; mt++)
#pragma unroll
      for (int r = 0; r < 4; r++) {
        int orow = mo + wm + mt * 16 + quad * 4 + r;
#pragma unroll
        for (int nt = 0; nt < 4; nt++) {
          int lcol = nl + wn + nt * 16 + col;
          Gb[(size_t)orow * 1024 + lcol] = (_Float16)acc[mt][nt][r];
        }
      }
  }
}

// =======================================================================
// K_FUSE: per (b, 16-t) block, BN=256. Separable logits, bound-max softmax,
// fp16 e-tiles, B-frags direct from L2. 4 barriers. 4 blocks/CU target.
// =======================================================================
__global__ __launch_bounds__(256, 4) void k_fuse(
    const _Float16* __restrict__ G,
    const float* __restrict__ dur, const float* __restrict__ sk,
    const int* __restrict__ frame_len,
    const float* __restrict__ hw, const float* __restrict__ hc,
    const float* __restrict__ mlpWw, const float* __restrict__ mlpbw,
    const float* __restrict__ mlpWc, const float* __restrict__ mlpbc,
    const float* __restrict__ lwb, const float* __restrict__ lcb,
    const float* __restrict__ LC, float* __restrict__ out) {
  __shared__ __align__(16) _Float16 Et[2][16][264];  // 16.9 KB
  __shared__ __align__(16) float4 Lbw4[256];         // A[l][q] (masked -1e30)
  __shared__ __align__(16) float4 Laux4[256];        // bc0', bc1', msk, -
  __shared__ float4 wredM[4];
  __shared__ float invL[16 * 4];
  __shared__ float wcL[16 * 8];

  int blk = blockIdx.x;
  int b = (blk & 7) * 2 + ((blk >> 3) & 1);  // b-pair per XCD: G stays in L2
  int tile = blk >> 4;                        // 0..62
  int t0 = tile * 16;
  int tid = threadIdx.x, wave = tid >> 6, lane = tid & 63;
  int quad = lane >> 4, col = lane & 15;

  // ---- phase A: per-l separable bases ----
  {
    int l = tid;
    float4 a0 = *(const float4*)&hw[((size_t)(b * 256 + l)) * 8];
    float4 a1 = *(const float4*)&hw[((size_t)(b * 256 + l)) * 8 + 4];
    float4 c0 = *(const float4*)&hc[((size_t)(b * 256 + l)) * 8];
    float4 c1 = *(const float4*)&hc[((size_t)(b * 256 + l)) * 8 + 4];
    float hwv[8] = {a0.x, a0.y, a0.z, a0.w, a1.x, a1.y, a1.z, a1.w};
    float hcv[8] = {c0.x, c0.y, c0.z, c0.w, c1.x, c1.y, c1.z, c1.w};
    float dl = dur[b * 256 + l];
    float skl = sk[b * 256 + l];
    float msk = (dl != 0.f) ? 1.f : 0.f;
    float A[4];
#pragma unroll
    for (int q = 0; q < 4; q++) {
      float a = mlpbw[q] + dl * mlpWw[4 + q] - skl * mlpWw[q];
#pragma unroll
      for (int ch = 0; ch < 8; ch++) a += hwv[ch] * mlpWw[(2 + ch) * 4 + q];
      A[q] = (msk != 0.f) ? a : -1e30f;
    }
    float bb0 = mlpbc[0] + dl * mlpWc[2] - skl * mlpWc[0];
    float bb1 = mlpbc[1] + dl * mlpWc[3] - skl * mlpWc[1];
#pragma unroll
    for (int ch = 0; ch < 8; ch++) {
      bb0 += hcv[ch] * mlpWc[(2 + ch) * 2 + 0];
      bb1 += hcv[ch] * mlpWc[(2 + ch) * 2 + 1];
    }
    float4 Av = {A[0], A[1], A[2], A[3]};
    Lbw4[l] = Av;
    float4 xv = {bb0, bb1, msk, 0.f};
    Laux4[l] = xv;
    float m0 = A[0], m1 = A[1], m2 = A[2], m3 = A[3];
#pragma unroll
    for (int off = 1; off < 64; off <<= 1) {
      m0 = fmaxf(m0, __shfl_xor(m0, off));
      m1 = fmaxf(m1, __shfl_xor(m1, off));
      m2 = fmaxf(m2, __shfl_xor(m2, off));
      m3 = fmaxf(m3, __shfl_xor(m3, off));
    }
    if (lane == 0) {
      float4 mv = {m0, m1, m2, m3};
      wredM[wave] = mv;
    }
  }
  __syncthreads();
  float4 W0 = wredM[0], W1 = wredM[1], W2 = wredM[2], W3 = wredM[3];
  float maxA[4] = {fmaxf(fmaxf(W0.x, W1.x), fmaxf(W2.x, W3.x)),
                   fmaxf(fmaxf(W0.y, W1.y), fmaxf(W2.y, W3.y)),
                   fmaxf(fmaxf(W0.z, W1.z), fmaxf(W2.z, W3.z)),
                   fmaxf(fmaxf(W0.w, W1.w), fmaxf(W2.w, W3.w))};

  int fl = frame_len[b];
  int tg = tid >> 5, seg = tid & 31;  // thread: rows {tg, tg+8} x 8 l's
  float mw0[4] = {mlpWw[0], mlpWw[1], mlpWw[2], mlpWw[3]};
  float mc0 = mlpWc[0], mc1 = mlpWc[1];
  float tp1v[2], tS0[2], tS1[2];
  bool livev[2];
#pragma unroll
  for (int ti = 0; ti < 2; ti++) {
    int t = t0 + tg + 8 * ti;
    livev[ti] = (t < fl);
    tp1v[ti] = (float)(t + 1);
    tS0[ti] = tp1v[ti] * mc0;
    tS1[ti] = tp1v[ti] * mc1;
  }

  int wn = wave * 64;
  f4 accF[4] = {};
  const _Float16* Gb = G + (size_t)b * 262144;

#pragma unroll
  for (int pp = 0; pp < 2; pp++) {
    if (pp) __syncthreads();  // previous pair's Et reads done
    int qa = pp * 2;
    float mm[2][2];
#pragma unroll
    for (int ti = 0; ti < 2; ti++) {
      mm[ti][0] = livev[ti] ? fmaxf(maxA[qa] + tp1v[ti] * mw0[qa], 0.f) : 1e30f;
      mm[ti][1] = livev[ti] ? fmaxf(maxA[qa + 1] + tp1v[ti] * mw0[qa + 1], 0.f) : 1e30f;
    }
    float s[2][2] = {}, pw0[2][2] = {}, pw1[2][2] = {};
    for (int jj = 0; jj < 8; jj++) {
      int l = jj * 32 + seg;
      float4 A4 = Lbw4[l];
      float4 ax = Laux4[l];
      float Aa = pp ? A4.z : A4.x;
      float Ab = pp ? A4.w : A4.y;
#pragma unroll
      for (int ti = 0; ti < 2; ti++) {
        float tp1 = tp1v[ti];
        float za = Aa + tp1 * mw0[qa];
        float zb = Ab + tp1 * mw0[qa + 1];
        float ea = __expf(swishf(za) - mm[ti][0]) * ax.z;
        float eb = __expf(swishf(zb) - mm[ti][1]) * ax.z;
        float cp0 = swishf(ax.x + tS0[ti]);
        float cp1 = swishf(ax.y + tS1[ti]);
        s[ti][0] += ea;  pw0[ti][0] += ea * cp0;  pw1[ti][0] += ea * cp1;
        s[ti][1] += eb;  pw0[ti][1] += eb * cp0;  pw1[ti][1] += eb * cp1;
        Et[0][tg + 8 * ti][l] = (_Float16)ea;
        Et[1][tg + 8 * ti][l] = (_Float16)eb;
      }
    }
#pragma unroll
    for (int off = 1; off < 32; off <<= 1) {
#pragma unroll
      for (int ti = 0; ti < 2; ti++)
#pragma unroll
        for (int e2 = 0; e2 < 2; e2++) {
          s[ti][e2] += __shfl_xor(s[ti][e2], off);
          pw0[ti][e2] += __shfl_xor(pw0[ti][e2], off);
          pw1[ti][e2] += __shfl_xor(pw1[ti][e2], off);
        }
    }
    if (seg == 0) {
#pragma unroll
      for (int ti = 0; ti < 2; ti++) {
        int row = tg + 8 * ti;
#pragma unroll
        for (int e2 = 0; e2 < 2; e2++) {
          int qq = qa + e2;
          float iv = livev[ti] ? __builtin_amdgcn_rcpf(s[ti][e2]) : 0.f;
          invL[row * 4 + qq] = iv;
          wcL[row * 8 + qq * 2 + 0] = pw0[ti][e2] * iv;
          wcL[row * 8 + qq * 2 + 1] = pw1[ti][e2] * iv;
        }
      }
    }
    __syncthreads();  // Et + invL ready
#pragma unroll
    for (int e2 = 0; e2 < 2; e2++) {
      int qq = qa + e2;
      f4 accq[4] = {};
#pragma unroll
      for (int k0 = 0; k0 < 256; k0 += 32) {
        v8h af = *(const v8h*)&Et[e2][col][k0 + quad * 8];
        v8h bf[4];
#pragma unroll
        for (int nt = 0; nt < 4; nt++)
          bf[nt] = *(const v8h*)(Gb + (size_t)(wn + nt * 16 + col) * 1024 +
                                 qq * 256 + k0 + quad * 8);
#pragma unroll
        for (int nt = 0; nt < 4; nt++)
          accq[nt] = __builtin_amdgcn_mfma_f32_16x16x32_f16(af, bf[nt],
                                                            accq[nt], 0, 0, 0);
      }
#pragma unroll
      for (int r = 0; r < 4; r++) {
        float iv = invL[(quad * 4 + r) * 4 + qq];
#pragma unroll
        for (int nt = 0; nt < 4; nt++) accF[nt][r] += accq[nt][r] * iv;
      }
    }
  }

  // ---- epilogue ----
#pragma unroll
  for (int nt = 0; nt < 4; nt++) {
    int oc = wn + nt * 16 + col;
    float bias = lwb[oc] + lcb[oc];
    float lc8[8];
#pragma unroll
    for (int jj = 0; jj < 8; jj++) lc8[jj] = LC[jj * 256 + oc];
#pragma unroll
    for (int r = 0; r < 4; r++) {
      int lr = quad * 4 + r;
      int trow = t0 + lr;
      if (trow < 1000) {
        float v = accF[nt][r] + bias;
#pragma unroll
        for (int jj = 0; jj < 8; jj++) v = fmaf(wcL[lr * 8 + jj], lc8[jj], v);
        out[((size_t)(b * 1000 + trow)) * 256 + oc] = v;
      }
    }
  }
}

// ---------- launch ----------
extern "C" void kernel_launch(void* const* d_in, const int* in_sizes, int n_in,
                              void* d_out, int out_size, void* d_ws, size_t ws_size,
                              hipStream_t stream) {
  const float* dur  = (const float*)d_in[0];
  const float* ph   = (const float*)d_in[1];
  const float* pjWw = (const float*)d_in[3];
  const float* pjbw = (const float*)d_in[4];
  const float* cvWw = (const float*)d_in[5];
  const float* cvbw = (const float*)d_in[6];
  const float* mlWw = (const float*)d_in[7];
  const float* mlbw = (const float*)d_in[8];
  const float* liWw = (const float*)d_in[9];
  const float* libw = (const float*)d_in[10];
  const float* pjWc = (const float*)d_in[11];
  const float* pjbc = (const float*)d_in[12];
  const float* cvWc = (const float*)d_in[13];
  const float* cvbc = (const float*)d_in[14];
  const float* mlWc = (const float*)d_in[15];
  const float* mlbc = (const float*)d_in[16];
  const float* liWc = (const float*)d_in[17];
  const float* libc = (const float*)d_in[18];
  float* out = (float*)d_out;

  float* f = (float*)d_ws;
  size_t o = 0;
  float* sk = f + o;            o += 4096;
  int* fl = (int*)(f + o);      o += 16;
  float* bK = f + o;            o += 64;
  unsigned short* Mb = (unsigned short*)(f + o); o += 6144;
  float* hw = f + o;            o += 16 * 256 * 8;
  float* hc = f + o;            o += 16 * 256 * 8;
  _Float16* G = (_Float16*)(f + o);              o += 2097152;  // 4.2M fp16
  unsigned short* phT = (unsigned short*)(f + o); o += 524288;
  unsigned short* LWT = (unsigned short*)(f + o); o += 131072;

  k_prep<<<1344, 256, 0, stream>>>(dur, ph, liWw, cvWw, pjWw, pjbw, cvWc, pjWc,
                                   pjbc, sk, fl, Mb, bK, LWT, phT);
  k_convG<<<272, 256, 0, stream>>>(phT, Mb, bK, cvbw, cvbc, dur, LWT, hw, hc, G);
  k_fuse<<<1008, 256, 0, stream>>>(G, dur, sk, fl, hw, hc, mlWw, mlbw, mlWc,
                                   mlbc, libw, libc, liWc, out);
}

// Round 7
// 178.201 us; speedup vs baseline: 1.1518x; 1.1518x over previous
//
#include <hip/hip_runtime.h>

// B=16, D=256, L=256, T=1000, K=3, DW=4, DC=2, CH=8

typedef short v8s __attribute__((ext_vector_type(8)));
typedef _Float16 v8h __attribute__((ext_vector_type(8)));
typedef float f4 __attribute__((ext_vector_type(4)));

__device__ __forceinline__ float bf2f(unsigned short h) {
  return __uint_as_float(((unsigned int)h) << 16);
}
__device__ __forceinline__ unsigned short f2bf(float f) {
  unsigned int u = __float_as_uint(f);
  u = (u + 0x7FFFu + ((u >> 16) & 1u)) >> 16;
  return (unsigned short)u;
}
__device__ __forceinline__ float swishf(float x) {
  return x * __builtin_amdgcn_rcpf(1.f + __expf(-x));
}

// =======================================================================
// K_PREP: level-0 work, branch on blockIdx.x
// =======================================================================
__global__ __launch_bounds__(256) void k_prep(
    const float* __restrict__ dur, const float* __restrict__ ph,
    const float* __restrict__ liWw,
    const float* __restrict__ cvWw, const float* __restrict__ pjWw,
    const float* __restrict__ pjbw,
    const float* __restrict__ cvWc, const float* __restrict__ pjWc,
    const float* __restrict__ pjbc,
    float* __restrict__ sk, int* __restrict__ frame_len,
    unsigned short* __restrict__ Mb, float* __restrict__ bK,
    unsigned short* __restrict__ LWT, unsigned short* __restrict__ phT) {
  __shared__ float sm[32 * 33];
  int blk = blockIdx.x, tid = threadIdx.x;
  if (blk < 16) {
    int b = blk, l = tid;
    float d = dur[b * 256 + l];
    sm[l] = d;
    __syncthreads();
    for (int off = 1; off < 256; off <<= 1) {
      float v = (l >= off) ? sm[l - off] : 0.f;
      __syncthreads();
      sm[l] += v;
      __syncthreads();
    }
    sk[b * 256 + l] = sm[l] - d;
    if (l == 255) {
      int fl = (int)rintf(sm[255]);
      frame_len[b] = min(max(fl, 0), 1000);
    }
  } else if (blk < 64) {
    int x = blk - 16;
    int br = x / 24, ck = x % 24;
    int ch = ck / 3, k = ck % 3;
    const float* convW = br ? cvWc : cvWw;
    const float* projW = br ? pjWc : pjWw;
    const float* projb = br ? pjbc : pjbw;
    int d = tid;
    float acc = 0.f;
    for (int o = 0; o < 256; o++)
      acc += convW[ch * 768 + o * 3 + k] * projW[o * 256 + d];
    Mb[(br * 24 + ck) * 256 + d] = f2bf(acc);
    if (d == 0) {
      float bb = 0.f;
      for (int o = 0; o < 256; o++)
        bb += convW[ch * 768 + o * 3 + k] * projb[o];
      bK[br * 24 + ck] = bb;
    }
  } else if (blk < 320) {
    int idx = blk - 64;
    int kt = idx & 31, ot = idx >> 5;
    int tx = tid & 31, ty = tid >> 5;
#pragma unroll
    for (int r = 0; r < 4; r++) {
      int row = ty + r * 8;
      sm[row * 33 + tx] = liWw[(size_t)(kt * 32 + row) * 256 + ot * 32 + tx];
    }
    __syncthreads();
#pragma unroll
    for (int r = 0; r < 4; r++) {
      int row = ty + r * 8;
      LWT[(size_t)(ot * 32 + row) * 1024 + kt * 32 + tx] =
          f2bf(sm[tx * 33 + row]);
    }
  } else {
    int idx = blk - 320;
    int ht = idx & 7, lt = (idx >> 3) & 7, b = idx >> 6;
    int tx = tid & 31, ty = tid >> 5;
#pragma unroll
    for (int r = 0; r < 4; r++) {
      int row = ty + r * 8;
      sm[row * 33 + tx] =
          ph[(size_t)b * 65536 + (size_t)(ht * 32 + row) * 256 + lt * 32 + tx];
    }
    __syncthreads();
#pragma unroll
    for (int r = 0; r < 4; r++) {
      int row = ty + r * 8;
      phT[(size_t)b * 65536 + (size_t)(lt * 32 + row) * 256 + ht * 32 + tx] =
          f2bf(sm[tx * 33 + row]);
    }
  }
}

// =======================================================================
// K_CONVG: blk [0,16)   = MFMA conv -> hw, hc
//          blk [16,272) = gemmG, barrier-less, frags direct from L2
// =======================================================================
__global__ __launch_bounds__(256) void k_convG(
    const unsigned short* __restrict__ phT, const unsigned short* __restrict__ Mb,
    const float* __restrict__ bK, const float* __restrict__ cvbw,
    const float* __restrict__ cvbc, const float* __restrict__ dur,
    const unsigned short* __restrict__ LWT,
    float* __restrict__ hw, float* __restrict__ hc,
    _Float16* __restrict__ G) {
  __shared__ __align__(16) float C[256 * 49];
  int blk = blockIdx.x;
  int tid = threadIdx.x, wave = tid >> 6, lane = tid & 63;
  int quad = lane >> 4, col = lane & 15;
  if (blk < 16) {
    int b = blk;
    int l0 = wave * 64;
    const unsigned short* Ab = phT + (size_t)b * 65536;
    f4 acc[4][3] = {};
#pragma unroll
    for (int k0 = 0; k0 < 256; k0 += 32) {
      v8s af[4], bf[3];
#pragma unroll
      for (int lt = 0; lt < 4; lt++)
        af[lt] = *(const v8s*)(Ab + (size_t)(l0 + lt * 16 + col) * 256 + k0 + quad * 8);
#pragma unroll
      for (int ct = 0; ct < 3; ct++)
        bf[ct] = *(const v8s*)(Mb + (size_t)(ct * 16 + col) * 256 + k0 + quad * 8);
#pragma unroll
      for (int lt = 0; lt < 4; lt++)
#pragma unroll
        for (int ct = 0; ct < 3; ct++)
          acc[lt][ct] = __builtin_amdgcn_mfma_f32_16x16x32_bf16(af[lt], bf[ct],
                                                                acc[lt][ct], 0, 0, 0);
    }
#pragma unroll
    for (int lt = 0; lt < 4; lt++)
#pragma unroll
      for (int ct = 0; ct < 3; ct++)
#pragma unroll
        for (int r = 0; r < 4; r++)
          C[(l0 + lt * 16 + quad * 4 + r) * 49 + ct * 16 + col] = acc[lt][ct][r];
    __syncthreads();
    int l = tid;
    float dv = dur[b * 256 + l];
    bool vld = (dv != 0.f);
#pragma unroll
    for (int br = 0; br < 2; br++) {
      const float* convb = br ? cvbc : cvbw;
      float* dst = br ? hc : hw;
#pragma unroll
      for (int ch = 0; ch < 8; ch++) {
        int ck = br * 24 + ch * 3;
        float v = convb[ch] + bK[ck + 1] + C[l * 49 + ck + 1];
        if (l > 0) v += bK[ck + 0] + C[(l - 1) * 49 + ck + 0];
        if (l < 255) v += bK[ck + 2] + C[(l + 1) * 49 + ck + 2];
        v = swishf(v);
        dst[((size_t)(b * 256 + l)) * 8 + ch] = vld ? v : 0.f;
      }
    }
  } else {
    int idx = blk - 16;
    int b = idx >> 4;
    int sub = idx & 15;
    int q = sub >> 2, quadr = sub & 3;
    int mo = (quadr >> 1) * 128, nl = (quadr & 1) * 128;
    int wm = (wave & 1) * 64, wn = (wave >> 1) * 64;
    const unsigned short* Ag = LWT + (size_t)q * 256;
    const unsigned short* Bg = phT + (size_t)b * 65536;
    f4 acc[4][4] = {};
#pragma unroll
    for (int k0 = 0; k0 < 256; k0 += 32) {
      v8s af[4], bf[4];
#pragma unroll
      for (int mt = 0; mt < 4; mt++)
        af[mt] = *(const v8s*)(Ag + (size_t)(mo + wm + mt * 16 + col) * 1024 +
                               k0 + quad * 8);
#pragma unroll
      for (int nt = 0; nt < 4; nt++)
        bf[nt] = *(const v8s*)(Bg + (size_t)(nl + wn + nt * 16 + col) * 256 +
                               k0 + quad * 8);
#pragma unroll
      for (int mt = 0; mt < 4; mt++)
#pragma unroll
        for (int nt = 0; nt < 4; nt++)
          acc[mt][nt] = __builtin_amdgcn_mfma_f32_16x16x32_bf16(af[mt], bf[nt],
                                                                acc[mt][nt], 0, 0, 0);
    }
    _Float16* Gb = G + (size_t)b * 262144 + q * 256;
#pragma unroll
    for (int mt = 0; mt < 4; mt++)
#pragma unroll
      for (int r = 0; r < 4; r++) {
        int orow = mo + wm + mt * 16 + quad * 4 + r;
#pragma unroll
        for (int nt = 0; nt < 4; nt++) {
          int lcol = nl + wn + nt * 16 + col;
          Gb[(size_t)orow * 1024 + lcol] = (_Float16)acc[mt][nt][r];
        }
      }
  }
}

// =======================================================================
// K_SOFT: normalized softmax weights -> w (fp16 [b][1024 rows][1024]), wc.
// Block = 16 t's. Wave = 4 t's; lane = (t_local, l16); each lane owns 16
// contiguous l's fully in registers (packed fp16). 4-shfl reductions.
// grid (63, 16).
// =======================================================================
__global__ __launch_bounds__(256) void k_soft(
    const float* __restrict__ dur, const float* __restrict__ sk,
    const int* __restrict__ frame_len,
    const float* __restrict__ hw, const float* __restrict__ hc,
    const float* __restrict__ mlpWw, const float* __restrict__ mlpbw,
    const float* __restrict__ mlpWc, const float* __restrict__ mlpbc,
    _Float16* __restrict__ w, float* __restrict__ wc) {
  __shared__ __align__(16) float4 Lbw4[256];   // A[l][q] (masked -1e30)
  __shared__ __align__(16) float4 Laux4[256];  // bc0', bc1', msk, -
  __shared__ float4 wredM[4];
  int b = blockIdx.y;
  int t0 = blockIdx.x * 16;
  int tid = threadIdx.x, wave = tid >> 6, lane = tid & 63;

  // ---- phase A: per-l separable bases (l = tid) ----
  {
    int l = tid;
    float4 a0 = *(const float4*)&hw[((size_t)(b * 256 + l)) * 8];
    float4 a1 = *(const float4*)&hw[((size_t)(b * 256 + l)) * 8 + 4];
    float4 c0 = *(const float4*)&hc[((size_t)(b * 256 + l)) * 8];
    float4 c1 = *(const float4*)&hc[((size_t)(b * 256 + l)) * 8 + 4];
    float hwv[8] = {a0.x, a0.y, a0.z, a0.w, a1.x, a1.y, a1.z, a1.w};
    float hcv[8] = {c0.x, c0.y, c0.z, c0.w, c1.x, c1.y, c1.z, c1.w};
    float dl = dur[b * 256 + l];
    float skl = sk[b * 256 + l];
    float msk = (dl != 0.f) ? 1.f : 0.f;
    float A[4];
#pragma unroll
    for (int q = 0; q < 4; q++) {
      float a = mlpbw[q] + dl * mlpWw[4 + q] - skl * mlpWw[q];
#pragma unroll
      for (int ch = 0; ch < 8; ch++) a += hwv[ch] * mlpWw[(2 + ch) * 4 + q];
      A[q] = (msk != 0.f) ? a : -1e30f;
    }
    float bb0 = mlpbc[0] + dl * mlpWc[2] - skl * mlpWc[0];
    float bb1 = mlpbc[1] + dl * mlpWc[3] - skl * mlpWc[1];
#pragma unroll
    for (int ch = 0; ch < 8; ch++) {
      bb0 += hcv[ch] * mlpWc[(2 + ch) * 2 + 0];
      bb1 += hcv[ch] * mlpWc[(2 + ch) * 2 + 1];
    }
    float4 Av = {A[0], A[1], A[2], A[3]};
    Lbw4[l] = Av;
    float4 xv = {bb0, bb1, msk, 0.f};
    Laux4[l] = xv;
    float m0 = A[0], m1 = A[1], m2 = A[2], m3 = A[3];
#pragma unroll
    for (int off = 1; off < 64; off <<= 1) {
      m0 = fmaxf(m0, __shfl_xor(m0, off));
      m1 = fmaxf(m1, __shfl_xor(m1, off));
      m2 = fmaxf(m2, __shfl_xor(m2, off));
      m3 = fmaxf(m3, __shfl_xor(m3, off));
    }
    if (lane == 0) {
      float4 mv = {m0, m1, m2, m3};
      wredM[wave] = mv;
    }
  }
  __syncthreads();
  float4 W0 = wredM[0], W1 = wredM[1], W2 = wredM[2], W3 = wredM[3];
  float maxA[4] = {fmaxf(fmaxf(W0.x, W1.x), fmaxf(W2.x, W3.x)),
                   fmaxf(fmaxf(W0.y, W1.y), fmaxf(W2.y, W3.y)),
                   fmaxf(fmaxf(W0.z, W1.z), fmaxf(W2.z, W3.z)),
                   fmaxf(fmaxf(W0.w, W1.w), fmaxf(W2.w, W3.w))};

  int fl = frame_len[b];
  int tl = wave * 4 + (lane >> 4);  // 0..15
  int l16 = lane & 15;
  int t = t0 + tl;
  bool live = (t < fl);
  float tp1 = (float)(t + 1);
  float mw0[4] = {mlpWw[0], mlpWw[1], mlpWw[2], mlpWw[3]};
  float mc0 = mlpWc[0], mc1 = mlpWc[1];
  float m[4];
#pragma unroll
  for (int q = 0; q < 4; q++)
    m[q] = live ? fmaxf(maxA[q] + tp1 * mw0[q], 0.f) : 1e30f;

  float s[4] = {}, pw[4][2] = {{}, {}, {}, {}};
  v8h eh[4][2];  // packed fp16 e, 16 per q
#pragma unroll
  for (int j = 0; j < 16; j++) {
    int l = l16 * 16 + j;
    float4 A4 = Lbw4[l];
    float4 ax = Laux4[l];
    float cp0 = swishf(ax.x + tp1 * mc0);
    float cp1 = swishf(ax.y + tp1 * mc1);
    float Aq[4] = {A4.x, A4.y, A4.z, A4.w};
#pragma unroll
    for (int q = 0; q < 4; q++) {
      float z = Aq[q] + tp1 * mw0[q];
      float e = __expf(swishf(z) - m[q]) * ax.z;
      eh[q][j >> 3][j & 7] = (_Float16)e;
      s[q] += e;
      pw[q][0] += e * cp0;
      pw[q][1] += e * cp1;
    }
  }
#pragma unroll
  for (int off = 1; off < 16; off <<= 1) {
#pragma unroll
    for (int q = 0; q < 4; q++) {
      s[q] += __shfl_xor(s[q], off);
      pw[q][0] += __shfl_xor(pw[q][0], off);
      pw[q][1] += __shfl_xor(pw[q][1], off);
    }
  }
  size_t base = ((size_t)b * 1024 + t) * 1024;
#pragma unroll
  for (int q = 0; q < 4; q++) {
    float iv = live ? __builtin_amdgcn_rcpf(s[q]) : 0.f;
    _Float16 ivh = (_Float16)iv;
    v8h w0 = eh[q][0] * ivh;
    v8h w1 = eh[q][1] * ivh;
    *(v8h*)(w + base + q * 256 + l16 * 16) = w0;
    *(v8h*)(w + base + q * 256 + l16 * 16 + 8) = w1;
    if (l16 == 0 && t < 1000) {
      wc[((size_t)(b * 1000 + t)) * 8 + q * 2 + 0] = pw[q][0] * iv;
      wc[((size_t)(b * 1000 + t)) * 8 + q * 2 + 1] = pw[q][1] * iv;
    }
  }
}

// =======================================================================
// K_OUT: out[b][t][o] = sum_kk w[b][t][kk]*G[b][o][kk] + biases + wc*LC
// 64x128 tile, K=1024, staged LDS + register prefetch. grid (32, 16).
// =======================================================================
__global__ __launch_bounds__(256) void k_out(const _Float16* __restrict__ w,
                                             const _Float16* __restrict__ G,
                                             const float* __restrict__ lwb,
                                             const float* __restrict__ lcb,
                                             const float* __restrict__ LC,
                                             const float* __restrict__ wc,
                                             float* __restrict__ out) {
  int b = blockIdx.y;
  int t0 = (blockIdx.x >> 1) * 64;
  int o0 = (blockIdx.x & 1) * 128;
  int tid = threadIdx.x, wave = tid >> 6, lane = tid & 63;
  int quad = lane >> 4, col = lane & 15;
  __shared__ __align__(16) _Float16 Asm[64 * 40];
  __shared__ __align__(16) _Float16 Bsm[128 * 40];
  __shared__ float bias_s[128];
  __shared__ float lcs[8][128];
  __shared__ float wcs[64][8];

  for (int i = tid; i < 128; i += 256) bias_s[i] = lwb[o0 + i] + lcb[o0 + i];
  for (int i = tid; i < 1024; i += 256)
    lcs[i >> 7][i & 127] = LC[(i >> 7) * 256 + o0 + (i & 127)];
  for (int i = tid; i < 512; i += 256) {
    int r = i >> 3, j = i & 7;
    int t = t0 + r;
    wcs[r][j] = (t < 1000) ? wc[((size_t)(b * 1000 + t)) * 8 + j] : 0.f;
  }

  int arow = wave * 16 + (lane >> 2);
  int aseg = lane & 3;
  const _Float16* Ag =
      w + (size_t)b * 1048576 + (size_t)(t0 + arow) * 1024 + aseg * 8;
  _Float16* Al = Asm + arow * 40 + aseg * 8;
  int brow = wave * 32 + (lane >> 2);
  const _Float16* Bg0 =
      G + (size_t)b * 262144 + (size_t)(o0 + brow) * 1024 + aseg * 8;
  const _Float16* Bg1 = Bg0 + 16 * 1024;
  _Float16* Bl0 = Bsm + brow * 40 + aseg * 8;
  _Float16* Bl1 = Bl0 + 16 * 40;

  int wm = (wave & 1) * 32, wn = (wave >> 1) * 64;
  f4 acc[2][4] = {};
  uint4 ra = *(const uint4*)Ag;
  uint4 rb0 = *(const uint4*)Bg0;
  uint4 rb1 = *(const uint4*)Bg1;
  for (int k0 = 0; k0 < 1024; k0 += 32) {
    __syncthreads();
    *(uint4*)Al = ra;
    *(uint4*)Bl0 = rb0;
    *(uint4*)Bl1 = rb1;
    __syncthreads();
    if (k0 + 32 < 1024) {
      ra = *(const uint4*)(Ag + k0 + 32);
      rb0 = *(const uint4*)(Bg0 + k0 + 32);
      rb1 = *(const uint4*)(Bg1 + k0 + 32);
    }
    v8h af[2], bf[4];
#pragma unroll
    for (int mt = 0; mt < 2; mt++)
      af[mt] = *(const v8h*)(Asm + (wm + mt * 16 + col) * 40 + quad * 8);
#pragma unroll
    for (int nt = 0; nt < 4; nt++)
      bf[nt] = *(const v8h*)(Bsm + (wn + nt * 16 + col) * 40 + quad * 8);
#pragma unroll
    for (int mt = 0; mt < 2; mt++)
#pragma unroll
      for (int nt = 0; nt < 4; nt++)
        acc[mt][nt] = __builtin_amdgcn_mfma_f32_16x16x32_f16(af[mt], bf[nt],
                                                             acc[mt][nt], 0, 0, 0);
  }
#pragma unroll
  for (int mt = 0; mt < 2; mt++)
#pragma unroll
    for (int r = 0; r < 4; r++) {
      int lrow = wm + mt * 16 + quad * 4 + r;
      int trow = t0 + lrow;
      if (trow < 1000) {
        float4 wa = *(const float4*)&wcs[lrow][0];
        float4 wb = *(const float4*)&wcs[lrow][4];
        float wcl[8] = {wa.x, wa.y, wa.z, wa.w, wb.x, wb.y, wb.z, wb.w};
#pragma unroll
        for (int nt = 0; nt < 4; nt++) {
          int oc = wn + nt * 16 + col;
          float v = acc[mt][nt][r] + bias_s[oc];
#pragma unroll
          for (int jj = 0; jj < 8; jj++) v = fmaf(wcl[jj], lcs[jj][oc], v);
          out[((size_t)(b * 1000 + trow)) * 256 + o0 + oc] = v;
        }
      }
    }
}

// ---------- launch ----------
extern "C" void kernel_launch(void* const* d_in, const int* in_sizes, int n_in,
                              void* d_out, int out_size, void* d_ws, size_t ws_size,
                              hipStream_t stream) {
  const float* dur  = (const float*)d_in[0];
  const float* ph   = (const float*)d_in[1];
  const float* pjWw = (const float*)d_in[3];
  const float* pjbw = (const float*)d_in[4];
  const float* cvWw = (const float*)d_in[5];
  const float* cvbw = (const float*)d_in[6];
  const float* mlWw = (const float*)d_in[7];
  const float* mlbw = (const float*)d_in[8];
  const float* liWw = (const float*)d_in[9];
  const float* libw = (const float*)d_in[10];
  const float* pjWc = (const float*)d_in[11];
  const float* pjbc = (const float*)d_in[12];
  const float* cvWc = (const float*)d_in[13];
  const float* cvbc = (const float*)d_in[14];
  const float* mlWc = (const float*)d_in[15];
  const float* mlbc = (const float*)d_in[16];
  const float* liWc = (const float*)d_in[17];
  const float* libc = (const float*)d_in[18];
  float* out = (float*)d_out;

  float* f = (float*)d_ws;
  size_t o = 0;
  float* sk = f + o;            o += 4096;
  int* fl = (int*)(f + o);      o += 16;
  float* bK = f + o;            o += 64;
  unsigned short* Mb = (unsigned short*)(f + o); o += 6144;
  float* hw = f + o;            o += 16 * 256 * 8;
  float* hc = f + o;            o += 16 * 256 * 8;
  float* wc = f + o;            o += 16 * 1000 * 8;
  _Float16* G = (_Float16*)(f + o);              o += 2097152;  // 8.4 MB
  _Float16* w = (_Float16*)(f + o);              o += 8388608;  // 33.5 MB (1024 rows/b)
  unsigned short* phT = (unsigned short*)(f + o); o += 524288;
  unsigned short* LWT = (unsigned short*)(f + o); o += 131072;

  k_prep<<<1344, 256, 0, stream>>>(dur, ph, liWw, cvWw, pjWw, pjbw, cvWc, pjWc,
                                   pjbc, sk, fl, Mb, bK, LWT, phT);
  k_convG<<<272, 256, 0, stream>>>(phT, Mb, bK, cvbw, cvbc, dur, LWT, hw, hc, G);
  k_soft<<<dim3(63, 16), 256, 0, stream>>>(dur, sk, fl, hw, hc, mlWw, mlbw,
                                           mlWc, mlbc, w, wc);
  k_out<<<dim3(32, 16), 256, 0, stream>>>(w, G, libw, libc, liWc, wc, out);
}

// Round 8
// 174.975 us; speedup vs baseline: 1.1730x; 1.0184x over previous
//
#include <hip/hip_runtime.h>

// B=16, D=256, L=256, T=1000, K=3, DW=4, DC=2, CH=8

typedef short v8s __attribute__((ext_vector_type(8)));
typedef _Float16 v8h __attribute__((ext_vector_type(8)));
typedef float f4 __attribute__((ext_vector_type(4)));

__device__ __forceinline__ float bf2f(unsigned short h) {
  return __uint_as_float(((unsigned int)h) << 16);
}
__device__ __forceinline__ unsigned short f2bf(float f) {
  unsigned int u = __float_as_uint(f);
  u = (u + 0x7FFFu + ((u >> 16) & 1u)) >> 16;
  return (unsigned short)u;
}
__device__ __forceinline__ float swishf(float x) {
  return x * __builtin_amdgcn_rcpf(1.f + __expf(-x));
}

// =======================================================================
// K_PREP: level-0 work, branch on blockIdx.x
// =======================================================================
__global__ __launch_bounds__(256) void k_prep(
    const float* __restrict__ dur, const float* __restrict__ ph,
    const float* __restrict__ liWw,
    const float* __restrict__ cvWw, const float* __restrict__ pjWw,
    const float* __restrict__ pjbw,
    const float* __restrict__ cvWc, const float* __restrict__ pjWc,
    const float* __restrict__ pjbc,
    float* __restrict__ sk, int* __restrict__ frame_len,
    unsigned short* __restrict__ Mb, float* __restrict__ bK,
    unsigned short* __restrict__ LWT, unsigned short* __restrict__ phT) {
  __shared__ float sm[32 * 33];
  int blk = blockIdx.x, tid = threadIdx.x;
  if (blk < 16) {
    int b = blk, l = tid;
    float d = dur[b * 256 + l];
    sm[l] = d;
    __syncthreads();
    for (int off = 1; off < 256; off <<= 1) {
      float v = (l >= off) ? sm[l - off] : 0.f;
      __syncthreads();
      sm[l] += v;
      __syncthreads();
    }
    sk[b * 256 + l] = sm[l] - d;
    if (l == 255) {
      int fl = (int)rintf(sm[255]);
      frame_len[b] = min(max(fl, 0), 1000);
    }
  } else if (blk < 64) {
    int x = blk - 16;
    int br = x / 24, ck = x % 24;
    int ch = ck / 3, k = ck % 3;
    const float* convW = br ? cvWc : cvWw;
    const float* projW = br ? pjWc : pjWw;
    const float* projb = br ? pjbc : pjbw;
    int d = tid;
    float acc = 0.f;
    for (int o = 0; o < 256; o++)
      acc += convW[ch * 768 + o * 3 + k] * projW[o * 256 + d];
    Mb[(br * 24 + ck) * 256 + d] = f2bf(acc);
    if (d == 0) {
      float bb = 0.f;
      for (int o = 0; o < 256; o++)
        bb += convW[ch * 768 + o * 3 + k] * projb[o];
      bK[br * 24 + ck] = bb;
    }
  } else if (blk < 320) {
    int idx = blk - 64;
    int kt = idx & 31, ot = idx >> 5;
    int tx = tid & 31, ty = tid >> 5;
#pragma unroll
    for (int r = 0; r < 4; r++) {
      int row = ty + r * 8;
      sm[row * 33 + tx] = liWw[(size_t)(kt * 32 + row) * 256 + ot * 32 + tx];
    }
    __syncthreads();
#pragma unroll
    for (int r = 0; r < 4; r++) {
      int row = ty + r * 8;
      LWT[(size_t)(ot * 32 + row) * 1024 + kt * 32 + tx] =
          f2bf(sm[tx * 33 + row]);
    }
  } else {
    int idx = blk - 320;
    int ht = idx & 7, lt = (idx >> 3) & 7, b = idx >> 6;
    int tx = tid & 31, ty = tid >> 5;
#pragma unroll
    for (int r = 0; r < 4; r++) {
      int row = ty + r * 8;
      sm[row * 33 + tx] =
          ph[(size_t)b * 65536 + (size_t)(ht * 32 + row) * 256 + lt * 32 + tx];
    }
    __syncthreads();
#pragma unroll
    for (int r = 0; r < 4; r++) {
      int row = ty + r * 8;
      phT[(size_t)b * 65536 + (size_t)(lt * 32 + row) * 256 + ht * 32 + tx] =
          f2bf(sm[tx * 33 + row]);
    }
  }
}

// =======================================================================
// K_CONVG: blk [0,16)   = MFMA conv -> hw, hc
//          blk [16,272) = gemmG, barrier-less, frags direct from L2
// =======================================================================
__global__ __launch_bounds__(256) void k_convG(
    const unsigned short* __restrict__ phT, const unsigned short* __restrict__ Mb,
    const float* __restrict__ bK, const float* __restrict__ cvbw,
    const float* __restrict__ cvbc, const float* __restrict__ dur,
    const unsigned short* __restrict__ LWT,
    float* __restrict__ hw, float* __restrict__ hc,
    _Float16* __restrict__ G) {
  __shared__ __align__(16) float C[256 * 49];
  int blk = blockIdx.x;
  int tid = threadIdx.x, wave = tid >> 6, lane = tid & 63;
  int quad = lane >> 4, col = lane & 15;
  if (blk < 16) {
    int b = blk;
    int l0 = wave * 64;
    const unsigned short* Ab = phT + (size_t)b * 65536;
    f4 acc[4][3] = {};
#pragma unroll
    for (int k0 = 0; k0 < 256; k0 += 32) {
      v8s af[4], bf[3];
#pragma unroll
      for (int lt = 0; lt < 4; lt++)
        af[lt] = *(const v8s*)(Ab + (size_t)(l0 + lt * 16 + col) * 256 + k0 + quad * 8);
#pragma unroll
      for (int ct = 0; ct < 3; ct++)
        bf[ct] = *(const v8s*)(Mb + (size_t)(ct * 16 + col) * 256 + k0 + quad * 8);
#pragma unroll
      for (int lt = 0; lt < 4; lt++)
#pragma unroll
        for (int ct = 0; ct < 3; ct++)
          acc[lt][ct] = __builtin_amdgcn_mfma_f32_16x16x32_bf16(af[lt], bf[ct],
                                                                acc[lt][ct], 0, 0, 0);
    }
#pragma unroll
    for (int lt = 0; lt < 4; lt++)
#pragma unroll
      for (int ct = 0; ct < 3; ct++)
#pragma unroll
        for (int r = 0; r < 4; r++)
          C[(l0 + lt * 16 + quad * 4 + r) * 49 + ct * 16 + col] = acc[lt][ct][r];
    __syncthreads();
    int l = tid;
    float dv = dur[b * 256 + l];
    bool vld = (dv != 0.f);
#pragma unroll
    for (int br = 0; br < 2; br++) {
      const float* convb = br ? cvbc : cvbw;
      float* dst = br ? hc : hw;
#pragma unroll
      for (int ch = 0; ch < 8; ch++) {
        int ck = br * 24 + ch * 3;
        float v = convb[ch] + bK[ck + 1] + C[l * 49 + ck + 1];
        if (l > 0) v += bK[ck + 0] + C[(l - 1) * 49 + ck + 0];
        if (l < 255) v += bK[ck + 2] + C[(l + 1) * 49 + ck + 2];
        v = swishf(v);
        dst[((size_t)(b * 256 + l)) * 8 + ch] = vld ? v : 0.f;
      }
    }
  } else {
    int idx = blk - 16;
    int b = idx >> 4;
    int sub = idx & 15;
    int q = sub >> 2, quadr = sub & 3;
    int mo = (quadr >> 1) * 128, nl = (quadr & 1) * 128;
    int wm = (wave & 1) * 64, wn = (wave >> 1) * 64;
    const unsigned short* Ag = LWT + (size_t)q * 256;
    const unsigned short* Bg = phT + (size_t)b * 65536;
    f4 acc[4][4] = {};
#pragma unroll
    for (int k0 = 0; k0 < 256; k0 += 32) {
      v8s af[4], bf[4];
#pragma unroll
      for (int mt = 0; mt < 4; mt++)
        af[mt] = *(const v8s*)(Ag + (size_t)(mo + wm + mt * 16 + col) * 1024 +
                               k0 + quad * 8);
#pragma unroll
      for (int nt = 0; nt < 4; nt++)
        bf[nt] = *(const v8s*)(Bg + (size_t)(nl + wn + nt * 16 + col) * 256 +
                               k0 + quad * 8);
#pragma unroll
      for (int mt = 0; mt < 4; mt++)
#pragma unroll
        for (int nt = 0; nt < 4; nt++)
          acc[mt][nt] = __builtin_amdgcn_mfma_f32_16x16x32_bf16(af[mt], bf[nt],
                                                                acc[mt][nt], 0, 0, 0);
    }
    _Float16* Gb = G + (size_t)b * 262144 + q * 256;
#pragma unroll
    for (int mt = 0; mt < 4; mt++)
#pragma unroll
      for (int r = 0; r < 4; r++) {
        int orow = mo + wm + mt * 16 + quad * 4 + r;
#pragma unroll
        for (int nt = 0; nt < 4; nt++) {
          int lcol = nl + wn + nt * 16 + col;
          Gb[(size_t)orow * 1024 + lcol] = (_Float16)acc[mt][nt][r];
        }
      }
  }
}

// =======================================================================
// K_SOFT: normalized softmax weights -> w (fp16 [b][1024 rows][1024]), wc.
// Wave = 4 t's; lane = (t_local, l16); 16 contiguous l's per lane in regs.
// LDS bases padded: idx(l) = l + (l>>4) -> conflict-free reads.
// grid (63, 16).
// =======================================================================
__global__ __launch_bounds__(256) void k_soft(
    const float* __restrict__ dur, const float* __restrict__ sk,
    const int* __restrict__ frame_len,
    const float* __restrict__ hw, const float* __restrict__ hc,
    const float* __restrict__ mlpWw, const float* __restrict__ mlpbw,
    const float* __restrict__ mlpWc, const float* __restrict__ mlpbc,
    _Float16* __restrict__ w, float* __restrict__ wc) {
  __shared__ __align__(16) float4 Lbw4[272];   // padded: idx = l + (l>>4)
  __shared__ __align__(16) float4 Laux4[272];  // bc0', bc1', msk, -
  __shared__ float4 wredM[4];
  int b = blockIdx.y;
  int t0 = blockIdx.x * 16;
  int tid = threadIdx.x, wave = tid >> 6, lane = tid & 63;

  // ---- phase A: per-l separable bases (l = tid) ----
  {
    int l = tid;
    float4 a0 = *(const float4*)&hw[((size_t)(b * 256 + l)) * 8];
    float4 a1 = *(const float4*)&hw[((size_t)(b * 256 + l)) * 8 + 4];
    float4 c0 = *(const float4*)&hc[((size_t)(b * 256 + l)) * 8];
    float4 c1 = *(const float4*)&hc[((size_t)(b * 256 + l)) * 8 + 4];
    float hwv[8] = {a0.x, a0.y, a0.z, a0.w, a1.x, a1.y, a1.z, a1.w};
    float hcv[8] = {c0.x, c0.y, c0.z, c0.w, c1.x, c1.y, c1.z, c1.w};
    float dl = dur[b * 256 + l];
    float skl = sk[b * 256 + l];
    float msk = (dl != 0.f) ? 1.f : 0.f;
    float A[4];
#pragma unroll
    for (int q = 0; q < 4; q++) {
      float a = mlpbw[q] + dl * mlpWw[4 + q] - skl * mlpWw[q];
#pragma unroll
      for (int ch = 0; ch < 8; ch++) a += hwv[ch] * mlpWw[(2 + ch) * 4 + q];
      A[q] = (msk != 0.f) ? a : -1e30f;
    }
    float bb0 = mlpbc[0] + dl * mlpWc[2] - skl * mlpWc[0];
    float bb1 = mlpbc[1] + dl * mlpWc[3] - skl * mlpWc[1];
#pragma unroll
    for (int ch = 0; ch < 8; ch++) {
      bb0 += hcv[ch] * mlpWc[(2 + ch) * 2 + 0];
      bb1 += hcv[ch] * mlpWc[(2 + ch) * 2 + 1];
    }
    int li = l + (l >> 4);
    float4 Av = {A[0], A[1], A[2], A[3]};
    Lbw4[li] = Av;
    float4 xv = {bb0, bb1, msk, 0.f};
    Laux4[li] = xv;
    float m0 = A[0], m1 = A[1], m2 = A[2], m3 = A[3];
#pragma unroll
    for (int off = 1; off < 64; off <<= 1) {
      m0 = fmaxf(m0, __shfl_xor(m0, off));
      m1 = fmaxf(m1, __shfl_xor(m1, off));
      m2 = fmaxf(m2, __shfl_xor(m2, off));
      m3 = fmaxf(m3, __shfl_xor(m3, off));
    }
    if (lane == 0) {
      float4 mv = {m0, m1, m2, m3};
      wredM[wave] = mv;
    }
  }
  __syncthreads();
  float4 W0 = wredM[0], W1 = wredM[1], W2 = wredM[2], W3 = wredM[3];
  float maxA[4] = {fmaxf(fmaxf(W0.x, W1.x), fmaxf(W2.x, W3.x)),
                   fmaxf(fmaxf(W0.y, W1.y), fmaxf(W2.y, W3.y)),
                   fmaxf(fmaxf(W0.z, W1.z), fmaxf(W2.z, W3.z)),
                   fmaxf(fmaxf(W0.w, W1.w), fmaxf(W2.w, W3.w))};

  int fl = frame_len[b];
  int tl = wave * 4 + (lane >> 4);  // 0..15
  int l16 = lane & 15;
  int t = t0 + tl;
  bool live = (t < fl);
  float tp1 = (float)(t + 1);
  float mw0[4] = {mlpWw[0], mlpWw[1], mlpWw[2], mlpWw[3]};
  float mc0 = mlpWc[0], mc1 = mlpWc[1];
  float m[4];
#pragma unroll
  for (int q = 0; q < 4; q++)
    m[q] = live ? fmaxf(maxA[q] + tp1 * mw0[q], 0.f) : 1e30f;

  float s[4] = {}, pw[4][2] = {{}, {}, {}, {}};
  v8h eh[4][2];  // packed fp16 e, 16 per q
  int lbase = l16 * 17;
#pragma unroll
  for (int j = 0; j < 16; j++) {
    float4 A4 = Lbw4[lbase + j];
    float4 ax = Laux4[lbase + j];
    float cp0 = swishf(ax.x + tp1 * mc0);
    float cp1 = swishf(ax.y + tp1 * mc1);
    float Aq[4] = {A4.x, A4.y, A4.z, A4.w};
#pragma unroll
    for (int q = 0; q < 4; q++) {
      float z = Aq[q] + tp1 * mw0[q];
      float e = __expf(swishf(z) - m[q]) * ax.z;
      eh[q][j >> 3][j & 7] = (_Float16)e;
      s[q] += e;
      pw[q][0] += e * cp0;
      pw[q][1] += e * cp1;
    }
  }
#pragma unroll
  for (int off = 1; off < 16; off <<= 1) {
#pragma unroll
    for (int q = 0; q < 4; q++) {
      s[q] += __shfl_xor(s[q], off);
      pw[q][0] += __shfl_xor(pw[q][0], off);
      pw[q][1] += __shfl_xor(pw[q][1], off);
    }
  }
  size_t base = ((size_t)b * 1024 + t) * 1024;
#pragma unroll
  for (int q = 0; q < 4; q++) {
    float iv = live ? __builtin_amdgcn_rcpf(s[q]) : 0.f;
    _Float16 ivh = (_Float16)iv;
    v8h w0 = eh[q][0] * ivh;
    v8h w1 = eh[q][1] * ivh;
    *(v8h*)(w + base + q * 256 + l16 * 16) = w0;
    *(v8h*)(w + base + q * 256 + l16 * 16 + 8) = w1;
    if (l16 == 0 && t < 1000) {
      wc[((size_t)(b * 1000 + t)) * 8 + q * 2 + 0] = pw[q][0] * iv;
      wc[((size_t)(b * 1000 + t)) * 8 + q * 2 + 1] = pw[q][1] * iv;
    }
  }
}

// =======================================================================
// K_OUT: out[b][t][o] = sum_kk w[b][t][kk]*G[b][o][kk] + biases + wc*LC
// 32x128 tile, K=1024, staged LDS + register prefetch. grid (64, 16),
// ~4 blocks/CU for cross-block latency hiding.
// =======================================================================
__global__ __launch_bounds__(256) void k_out(const _Float16* __restrict__ w,
                                             const _Float16* __restrict__ G,
                                             const float* __restrict__ lwb,
                                             const float* __restrict__ lcb,
                                             const float* __restrict__ LC,
                                             const float* __restrict__ wc,
                                             float* __restrict__ out) {
  int b = blockIdx.y;
  int t0 = (blockIdx.x >> 1) * 32;
  int o0 = (blockIdx.x & 1) * 128;
  int tid = threadIdx.x, wave = tid >> 6, lane = tid & 63;
  int quad = lane >> 4, col = lane & 15;
  __shared__ __align__(16) _Float16 Asm[32 * 40];
  __shared__ __align__(16) _Float16 Bsm[128 * 40];
  __shared__ float bias_s[128];
  __shared__ float lcs[8][128];
  __shared__ float wcs[32][8];

  for (int i = tid; i < 128; i += 256) bias_s[i] = lwb[o0 + i] + lcb[o0 + i];
  for (int i = tid; i < 1024; i += 256)
    lcs[i >> 7][i & 127] = LC[(i >> 7) * 256 + o0 + (i & 127)];
  {
    int r = tid >> 3, j = tid & 7;
    int t = t0 + r;
    wcs[r][j] = (t < 1000) ? wc[((size_t)(b * 1000 + t)) * 8 + j] : 0.f;
  }

  bool aload = tid < 128;
  int arow = tid >> 2, aseg = tid & 3;  // rows 0..31 (tid<128)
  const _Float16* Ag =
      w + (size_t)b * 1048576 + (size_t)(t0 + arow) * 1024 + aseg * 8;
  _Float16* Al = Asm + arow * 40 + aseg * 8;
  int brow = wave * 32 + (lane >> 2), bseg = lane & 3;
  const _Float16* Bg0 =
      G + (size_t)b * 262144 + (size_t)(o0 + brow) * 1024 + bseg * 8;
  const _Float16* Bg1 = Bg0 + 16 * 1024;
  _Float16* Bl0 = Bsm + brow * 40 + bseg * 8;
  _Float16* Bl1 = Bl0 + 16 * 40;

  int wm = (wave & 1) * 16, wn = (wave >> 1) * 64;
  f4 acc[4] = {};
  uint4 ra = {0, 0, 0, 0};
  if (aload) ra = *(const uint4*)Ag;
  uint4 rb0 = *(const uint4*)Bg0;
  uint4 rb1 = *(const uint4*)Bg1;
  for (int k0 = 0; k0 < 1024; k0 += 32) {
    __syncthreads();
    if (aload) *(uint4*)Al = ra;
    *(uint4*)Bl0 = rb0;
    *(uint4*)Bl1 = rb1;
    __syncthreads();
    if (k0 + 32 < 1024) {
      if (aload) ra = *(const uint4*)(Ag + k0 + 32);
      rb0 = *(const uint4*)(Bg0 + k0 + 32);
      rb1 = *(const uint4*)(Bg1 + k0 + 32);
    }
    v8h af = *(const v8h*)(Asm + (wm + col) * 40 + quad * 8);
    v8h bf[4];
#pragma unroll
    for (int nt = 0; nt < 4; nt++)
      bf[nt] = *(const v8h*)(Bsm + (wn + nt * 16 + col) * 40 + quad * 8);
#pragma unroll
    for (int nt = 0; nt < 4; nt++)
      acc[nt] = __builtin_amdgcn_mfma_f32_16x16x32_f16(af, bf[nt],
                                                       acc[nt], 0, 0, 0);
  }
#pragma unroll
  for (int r = 0; r < 4; r++) {
    int lrow = wm + quad * 4 + r;
    int trow = t0 + lrow;
    if (trow < 1000) {
      float4 wa = *(const float4*)&wcs[lrow][0];
      float4 wb = *(const float4*)&wcs[lrow][4];
      float wcl[8] = {wa.x, wa.y, wa.z, wa.w, wb.x, wb.y, wb.z, wb.w};
#pragma unroll
      for (int nt = 0; nt < 4; nt++) {
        int oc = wn + nt * 16 + col;
        float v = acc[nt][r] + bias_s[oc];
#pragma unroll
        for (int jj = 0; jj < 8; jj++) v = fmaf(wcl[jj], lcs[jj][oc], v);
        out[((size_t)(b * 1000 + trow)) * 256 + o0 + oc] = v;
      }
    }
  }
}

// ---------- launch ----------
extern "C" void kernel_launch(void* const* d_in, const int* in_sizes, int n_in,
                              void* d_out, int out_size, void* d_ws, size_t ws_size,
                              hipStream_t stream) {
  const float* dur  = (const float*)d_in[0];
  const float* ph   = (const float*)d_in[1];
  const float* pjWw = (const float*)d_in[3];
  const float* pjbw = (const float*)d_in[4];
  const float* cvWw = (const float*)d_in[5];
  const float* cvbw = (const float*)d_in[6];
  const float* mlWw = (const float*)d_in[7];
  const float* mlbw = (const float*)d_in[8];
  const float* liWw = (const float*)d_in[9];
  const float* libw = (const float*)d_in[10];
  const float* pjWc = (const float*)d_in[11];
  const float* pjbc = (const float*)d_in[12];
  const float* cvWc = (const float*)d_in[13];
  const float* cvbc = (const float*)d_in[14];
  const float* mlWc = (const float*)d_in[15];
  const float* mlbc = (const float*)d_in[16];
  const float* liWc = (const float*)d_in[17];
  const float* libc = (const float*)d_in[18];
  float* out = (float*)d_out;

  float* f = (float*)d_ws;
  size_t o = 0;
  float* sk = f + o;            o += 4096;
  int* fl = (int*)(f + o);      o += 16;
  float* bK = f + o;            o += 64;
  unsigned short* Mb = (unsigned short*)(f + o); o += 6144;
  float* hw = f + o;            o += 16 * 256 * 8;
  float* hc = f + o;            o += 16 * 256 * 8;
  float* wc = f + o;            o += 16 * 1000 * 8;
  _Float16* G = (_Float16*)(f + o);              o += 2097152;  // 8.4 MB
  _Float16* w = (_Float16*)(f + o);              o += 8388608;  // 33.5 MB
  unsigned short* phT = (unsigned short*)(f + o); o += 524288;
  unsigned short* LWT = (unsigned short*)(f + o); o += 131072;

  k_prep<<<1344, 256, 0, stream>>>(dur, ph, liWw, cvWw, pjWw, pjbw, cvWc, pjWc,
                                   pjbc, sk, fl, Mb, bK, LWT, phT);
  k_convG<<<272, 256, 0, stream>>>(phT, Mb, bK, cvbw, cvbc, dur, LWT, hw, hc, G);
  k_soft<<<dim3(63, 16), 256, 0, stream>>>(dur, sk, fl, hw, hc, mlWw, mlbw,
                                           mlWc, mlbc, w, wc);
  k_out<<<dim3(64, 16), 256, 0, stream>>>(w, G, libw, libc, liWc, wc, out);
}